// Round 10
// baseline (2286.290 us; speedup 1.0000x reference)
//
#include <hip/hip_runtime.h>

// Encoder: 2-layer LSTM (H1=64, H2=32, IN=2), B=512, T=4096, + FC [32->16].
// R10: R9's fp16-dot2 K-sliced design rebalanced from 4-wave to 8-wave blocks
// (2 blocks/CU -> 4 waves/SIMD instead of 2) to fill the 29% issue bubbles.
//   waves 4..7 = L1: QUAD = unit. lane s=l&3: h=s&1 K-half, p=s>>1 gate-pair.
//     Each lane: rows (2p, 2p+1) x 32-half slice = 32 fdot2, 8 h8 weights.
//     xor1 reduce -> lanes hold full 64-dots of both rows; lane activates
//     gate 2p+h; quad DPP broadcasts gather i,f,g,o; cc redundant per quad.
//   waves 0..3 = L2: OCTET = unit (one step behind). lane j=l&7: q=j&3
//     K-quarter, p2=j>>2 gate-pair. 2 rows x 24-half slice of h1(64)++h2(32),
//     xor1+xor2 reduce, activate gate 2p2+(l&1), gather via pair-swap +
//     row_half_mirror + selects.
//   x: double-buffered LDS stage written one chunk ahead (uniform ds_read_b64
//     broadcast per step) -- replaces slow readlanes.
// Weights 24-32 VGPRs/lane: far under allocator rungs -> resident by default
// (R2-R7 lesson: never exceed the rung; R8/R9 proved small sets stay).

#define TT 4096
#define BB 512

typedef float    f4  __attribute__((ext_vector_type(4)));
typedef int      i4  __attribute__((ext_vector_type(4)));
typedef _Float16 h2v __attribute__((ext_vector_type(2)));
typedef _Float16 h8  __attribute__((ext_vector_type(8)));   // 4 VGPRs

__device__ __forceinline__ float fexp2(float x){ return __builtin_amdgcn_exp2f(x); }
__device__ __forceinline__ float frcp (float x){ return __builtin_amdgcn_rcpf(x); }
__device__ __forceinline__ float sigm (float x){ return frcp(1.0f + fexp2(x * -1.4426950408889634f)); }
__device__ __forceinline__ float tanh_(float x){ return 1.0f - 2.0f * frcp(1.0f + fexp2(x * 2.8853900817779268f)); }

// DPP: pure move (gather). 0xB1=[1,0,3,2]; 0x00/0x55/0xAA/0xFF=quad bcast;
// 0x141=row_half_mirror (j <-> 7-j within each 8-lane group).
template<int CTRL>
__device__ __forceinline__ float qperm(float v){
  const int s = __builtin_bit_cast(int, v);
  return __builtin_bit_cast(float, __builtin_amdgcn_update_dpp(s, s, CTRL, 0xF, 0xF, true));
}
__device__ __forceinline__ h2v bch(int s){ return __builtin_bit_cast(h2v, s); }
__device__ __forceinline__ float dot8(h8 a, i4 bi, float c){
  const i4 ai = __builtin_bit_cast(i4, a);
  c = __builtin_amdgcn_fdot2(bch(ai.x), bch(bi.x), c, false);
  c = __builtin_amdgcn_fdot2(bch(ai.y), bch(bi.y), c, false);
  c = __builtin_amdgcn_fdot2(bch(ai.z), bch(bi.z), c, false);
  c = __builtin_amdgcn_fdot2(bch(ai.w), bch(bi.w), c, false);
  return c;
}
__device__ __forceinline__ h8 ldh8(const float* p){
  const f4 a = ((const f4*)p)[0], b = ((const f4*)p)[1];
  h8 r;
  r[0]=(_Float16)a.x; r[1]=(_Float16)a.y; r[2]=(_Float16)a.z; r[3]=(_Float16)a.w;
  r[4]=(_Float16)b.x; r[5]=(_Float16)b.y; r[6]=(_Float16)b.z; r[7]=(_Float16)b.w;
  return r;
}

extern "C" __global__ __launch_bounds__(512, 4) void lstm_enc_kernel(
    const float* __restrict__ x,
    const float* __restrict__ Wih1, const float* __restrict__ Whh1,
    const float* __restrict__ bih1, const float* __restrict__ bhh1,
    const float* __restrict__ Wih2, const float* __restrict__ Whh2,
    const float* __restrict__ bih2, const float* __restrict__ bhh2,
    const float* __restrict__ Wfc,  const float* __restrict__ bfc,
    float* __restrict__ out)
{
    const int tid = threadIdx.x;
    const int l   = tid & 63;
    const int wv  = __builtin_amdgcn_readfirstlane(tid >> 6);   // 0..7, scalar
    const bool isL1 = (wv >= 4);
    const int b   = blockIdx.x;

    // hh[buf][0:64) = h1 halves, hh[buf][64:96) = h2 halves
    __shared__ __align__(16) _Float16 hh[2][96];
    __shared__ __align__(16) float    xs[2][128];   // [buf][64 steps x 2]

    // ---- L1 indices (waves 4..7): quad = unit ----
    const int u1 = ((wv - 4) & 3) * 16 + (l >> 2);
    const int h1h = l & 1;            // K-half
    const int p1  = (l >> 1) & 1;     // gate-pair
    const int rA1 = (2 * p1) * 64 + u1;
    const int rB1 = rA1 + 64;         // (2p1+1)*64 + u1

    // ---- L2 indices (waves 0..3): octet = unit ----
    const int u2 = (wv & 3) * 8 + (l >> 3);
    const int q2 = l & 3;             // K-quarter
    const int p2 = (l >> 2) & 1;      // gate-pair
    const int rA2 = (2 * p2) * 32 + u2;
    const int rB2 = rA2 + 32;

    // ---- weight pointers: single unconditional load path, ternary addrs ----
    // L1 row slice: Whh1[row][32*h1h .. +32) -> 4 h8 per row.
    // L2 row slice: concat(Wih2[row][0:64], Whh2[row][0:32]) floats
    //   [24*q2 .. +24) -> 3 h8 per row (8-float chunks never straddle 64).
#define CAT2(R, F) ((F) < 64 ? (Wih2 + (R)*64 + (F)) : (Whh2 + (R)*32 + (F) - 64))
    const int f0 = 24 * q2;
    const float* pa0 = isL1 ? (Whh1 + rA1*64 + 32*h1h +  0) : CAT2(rA2, f0 + 0);
    const float* pa1 = isL1 ? (Whh1 + rA1*64 + 32*h1h +  8) : CAT2(rA2, f0 + 8);
    const float* pa2 = isL1 ? (Whh1 + rA1*64 + 32*h1h + 16) : CAT2(rA2, f0 + 16);
    const float* pa3 = isL1 ? (Whh1 + rA1*64 + 32*h1h + 24) : CAT2(rA2, f0 + 16);
    const float* pb0 = isL1 ? (Whh1 + rB1*64 + 32*h1h +  0) : CAT2(rB2, f0 + 0);
    const float* pb1 = isL1 ? (Whh1 + rB1*64 + 32*h1h +  8) : CAT2(rB2, f0 + 8);
    const float* pb2 = isL1 ? (Whh1 + rB1*64 + 32*h1h + 16) : CAT2(rB2, f0 + 16);
    const float* pb3 = isL1 ? (Whh1 + rB1*64 + 32*h1h + 24) : CAT2(rB2, f0 + 16);
#undef CAT2
    h8 w0 = ldh8(pa0), w1 = ldh8(pa1), w2 = ldh8(pa2), w3 = ldh8(pa3);
    h8 w4 = ldh8(pb0), w5 = ldh8(pb1), w6 = ldh8(pb2), w7 = ldh8(pb3);

    // biases / x-weights: counted once (zeroed on non-first-slice lanes)
    const bool fs = isL1 ? (h1h == 0) : (q2 == 0);
    const float bbA = fs ? (isL1 ? (bih1[rA1] + bhh1[rA1]) : (bih2[rA2] + bhh2[rA2])) : 0.f;
    const float bbB = fs ? (isL1 ? (bih1[rB1] + bhh1[rB1]) : (bih2[rB2] + bhh2[rB2])) : 0.f;
    const float wxA0 = (isL1 && fs) ? Wih1[rA1*2 + 0] : 0.f;
    const float wxA1 = (isL1 && fs) ? Wih1[rA1*2 + 1] : 0.f;
    const float wxB0 = (isL1 && fs) ? Wih1[rB1*2 + 0] : 0.f;
    const float wxB1 = (isL1 && fs) ? Wih1[rB1*2 + 1] : 0.f;

    // tanh-blend flag: activated gate == 2 (g). L1: lane (l&3)==2.
    // L2: gate = 2*p2 + (l&1) == 2  ->  (l&7)==4 or 6.
    const float tf = isL1 ? (((l & 3) == 2) ? 1.f : 0.f)
                          : ((((l & 7) == 4) || ((l & 7) == 6)) ? 1.f : 0.f);

    const float2* xb2 = (const float2*)(x + (size_t)b * (TT * 2));
    float2 vxn = make_float2(0.f, 0.f);
    if (isL1) {
        const float2 c0 = xb2[l];                 // chunk 0
        ((float2*)xs[0])[l] = c0;                 // all L1 waves write same data
        vxn = xb2[64 + l];                        // chunk 1 (written at t=0)
    }
    if (tid < 96) ((int*)hh)[tid] = 0;            // zero both h buffers
    __syncthreads();

    float cc = 0.f;   // c1 (L1 lanes) / c2 (L2 lanes), redundant per quad/octet

    // t in [0, TT]: L1 computes step t (t<TT); L2 computes step t-1 (t>0).
    for (int t = 0; t <= TT; ++t) {
        const int rb = t & 1;
        const int wb = rb ^ 1;
        const i4* hb = (const i4*)hh[rb];

        if (isL1) {
            if (t < TT) {
                if ((t & 63) == 0) {
                    const int c = t >> 6;
                    if (t + 64 < TT) ((float2*)xs[(c + 1) & 1])[l] = vxn;   // chunk c+1
                    if (t + 128 < TT) vxn = xb2[(c + 2) * 64 + l];          // chunk c+2
                }
                const float2 xv = ((const float2*)xs[(t >> 6) & 1])[t & 63]; // uniform

                // h1(t-1) K-half slice: bytes [64*h1h, +64) -> 4 x b128
                const i4 H0 = hb[4*h1h+0], H1 = hb[4*h1h+1];
                const i4 H2 = hb[4*h1h+2], H3 = hb[4*h1h+3];

                float r0 = bbA, r1 = bbB;
                r0 = dot8(w0,H0,r0); r0 = dot8(w1,H1,r0);
                r0 = dot8(w2,H2,r0); r0 = dot8(w3,H3,r0);
                r1 = dot8(w4,H0,r1); r1 = dot8(w5,H1,r1);
                r1 = dot8(w6,H2,r1); r1 = dot8(w7,H3,r1);
                r0 = fmaf(wxA0, xv.x, fmaf(wxA1, xv.y, r0));
                r1 = fmaf(wxB0, xv.x, fmaf(wxB1, xv.y, r1));
                // xor1: combine K-halves -> both pair lanes hold full sums
                r0 += qperm<0xB1>(r0);
                r1 += qperm<0xB1>(r1);

                // lane activates gate 2p1 + (l&1)
                const float pre = (l & 1) ? r1 : r0;
                const float pa  = fmaf(tf, pre, pre);       // x or 2x
                const float sa  = sigm(pa);
                const float act = fmaf(tf, sa - 1.f, sa);   // sigm or tanh
                const float gi = qperm<0x00>(act);
                const float gf = qperm<0x55>(act);
                const float gg = qperm<0xAA>(act);
                const float go = qperm<0xFF>(act);
                cc = fmaf(gf, cc, gi * gg);
                const float hv = go * tanh_(cc);
                if ((l & 3) == 0) hh[wb][u1] = (_Float16)hv;
            }
        } else if (t > 0) {
            // h1(t-1)++h2(t-2) K-quarter slice: bytes [48*q2, +48) -> 3 x b128
            const i4 H0 = hb[3*q2+0], H1 = hb[3*q2+1], H2 = hb[3*q2+2];

            float r0 = bbA, r1 = bbB;
            r0 = dot8(w0,H0,r0); r0 = dot8(w1,H1,r0); r0 = dot8(w2,H2,r0);
            r1 = dot8(w4,H0,r1); r1 = dot8(w5,H1,r1); r1 = dot8(w6,H2,r1);
            // xor1 + xor2: combine the 4 K-quarters within each quad
            r0 += qperm<0xB1>(r0); r0 += qperm<0x4E>(r0);
            r1 += qperm<0xB1>(r1); r1 += qperm<0x4E>(r1);

            // lane activates gate 2p2 + (l&1); quad0 of octet = (i,f), quad1 = (g,o)
            const float pre = (l & 1) ? r1 : r0;
            const float pa  = fmaf(tf, pre, pre);
            const float sa  = sigm(pa);
            const float act = fmaf(tf, sa - 1.f, sa);
            const float vp  = qperm<0xB1>(act);             // pair partner
            const float eg  = (l & 1) ? vp  : act;          // even gate of this quad
            const float og  = (l & 1) ? act : vp;           // odd gate
            const float meg = qperm<0x141>(eg);             // other quad's even gate
            const float mog = qperm<0x141>(og);
            const bool hiq = (l & 4) != 0;                  // quad1 within octet
            const float i2 = hiq ? meg : eg;
            const float f2 = hiq ? mog : og;
            const float gv = hiq ? eg  : meg;
            const float o2 = hiq ? og  : mog;
            cc = fmaf(f2, cc, i2 * gv);
            const float hv = o2 * tanh_(cc);
            if ((l & 7) == 0) hh[wb][64 + u2] = (_Float16)hv;
        }
        __syncthreads();
    }

    // final h2(TT-1) was written at t=TT into hh[1][64:96)
    if (tid < 16) {
        float s = bfc[tid];
        const float* wr = Wfc + tid * 32;
        #pragma unroll
        for (int k = 0; k < 32; ++k) s = fmaf(wr[k], (float)hh[1][64 + k], s);
        out[b * 16 + tid] = s;
    }
}

extern "C" void kernel_launch(void* const* d_in, const int* in_sizes, int n_in,
                              void* d_out, int out_size, void* d_ws, size_t ws_size,
                              hipStream_t stream) {
    const float* x    = (const float*)d_in[0];
    const float* Wih1 = (const float*)d_in[1];
    const float* Whh1 = (const float*)d_in[2];
    const float* bih1 = (const float*)d_in[3];
    const float* bhh1 = (const float*)d_in[4];
    const float* Wih2 = (const float*)d_in[5];
    const float* Whh2 = (const float*)d_in[6];
    const float* bih2 = (const float*)d_in[7];
    const float* bhh2 = (const float*)d_in[8];
    const float* Wfc  = (const float*)d_in[9];
    const float* bfc  = (const float*)d_in[10];

    hipLaunchKernelGGL(lstm_enc_kernel, dim3(BB), dim3(512), 0, stream,
        x, Wih1, Whh1, bih1, bhh1, Wih2, Whh2, bih2, bhh2, Wfc, bfc,
        (float*)d_out);
}